// Round 7
// baseline (167.281 us; speedup 1.0000x reference)
//
#include <hip/hip_runtime.h>
#include <hip/hip_bf16.h>

// ReasoningMultiHeadAttention: B=4 S=2048 HID=1024 NH=16 DH=64. All I/O fp32.
// prep: 6x W -> bf16 W^T pre-swizzled (wt, ws) ; x -> bf16 xb pre-swizzled (in d_out!)
// gated8: dual-B GEMM, 4 phases/K-tile, counted vmcnt(4)/(2) NEVER 0, XCD swizzle
// plain8<bf16>: xb @ WvT + bv -> vv ; TRIPLE-buffered LDS, vmcnt(6) never 0
// attn: per-token 16x16 cross-head attn -> ar (ws, swizzled+scrambled)
// plain8<f32>: ar @ WoT + bo -> d_out (overwrites xb/kg scratch, all dead)
// ws usage: [0:12M wt][12:28M qg][28:44M vv][44:60M ar] = 60 MB
// d_out scratch: [0:16M xb][16:32M kg] until final GEMM rewrites all of d_out.

typedef __attribute__((ext_vector_type(8))) short short8;
typedef __attribute__((ext_vector_type(4))) short short4v;
typedef __attribute__((ext_vector_type(4))) float f32x4;

#define HID 1024
#define NTOK 8192
#define WT_ELEMS (1024 * 1024)

__device__ __forceinline__ short f2bs(float f) {
  __hip_bfloat16 h = __float2bfloat16(f);
  return *reinterpret_cast<short*>(&h);
}
__device__ __forceinline__ float bs2f(short s) {
  __hip_bfloat16 h;
  *reinterpret_cast<short*>(&h) = s;
  return __bfloat162float(h);
}
__device__ __forceinline__ void gload16(const void* g, void* l) {
  __builtin_amdgcn_global_load_lds(
      (const __attribute__((address_space(1))) void*)g,
      (__attribute__((address_space(3))) void*)l, 16, 0, 0);
}

#define BAR() asm volatile("s_barrier" ::: "memory")
#define VMWAIT(N) asm volatile("s_waitcnt vmcnt(" #N ")" ::: "memory")
#define LGKM0 do { asm volatile("s_waitcnt lgkmcnt(0)" ::: "memory"); \
                   __builtin_amdgcn_sched_barrier(0); } while (0)
#define SCB __builtin_amdgcn_sched_barrier(0)
#define PRIO1 __builtin_amdgcn_s_setprio(1)
#define PRIO0 __builtin_amdgcn_s_setprio(0)
#define MFMA16x16 __builtin_amdgcn_mfma_f32_16x16x32_bf16

// ---------------- prep: W transposes (z<6) + x fp32->bf16 convert ----------
// WT[n][ (k&~63) | ((k&63) ^ ((n&7)<<3)) ] = bf16(W[k][n])
// XB[row][ (k&~63) | ((k&63) ^ ((row&7)<<3)) ] = bf16(x[row][k])
__global__ __launch_bounds__(256) void prep_kernel(
    const float* __restrict__ W0, const float* __restrict__ W1,
    const float* __restrict__ W2, const float* __restrict__ W3,
    const float* __restrict__ W4, const float* __restrict__ W5,
    const float* __restrict__ X, short* __restrict__ WT, short* __restrict__ XB)
{
  __shared__ short sT[64][68];
  const int bid = blockIdx.x, tid = threadIdx.x;
  if (bid < 1536) {
    const int z = bid >> 8, rem = bid & 255;
    const float* W = z == 0 ? W0 : z == 1 ? W1 : z == 2 ? W2 : z == 3 ? W3
                   : z == 4 ? W4 : W5;
    short* OUT = WT + (size_t)z * WT_ELEMS;
    const int k0 = (rem & 15) * 64, n0 = (rem >> 4) * 64;
    #pragma unroll
    for (int i = 0; i < 4; i++) {
      const int li = tid + i * 256;
      const int kr = li >> 4, c4 = (li & 15) << 2;
      const f32x4 wv = *reinterpret_cast<const f32x4*>(&W[(size_t)(k0 + kr) * HID + n0 + c4]);
      short4v s4;
      #pragma unroll
      for (int j = 0; j < 4; j++) s4[j] = f2bs(wv[j]);
      *reinterpret_cast<short4v*>(&sT[kr][c4]) = s4;
    }
    __syncthreads();
    #pragma unroll
    for (int i = 0; i < 4; i++) {
      const int li = tid + i * 256;
      const int nr = li >> 4, k4 = (li & 15) << 2;
      short4v o;
      #pragma unroll
      for (int j = 0; j < 4; j++) o[j] = sT[k4 + j][nr];
      const int kcol = (k0 + k4) ^ ((nr & 7) << 3);
      *reinterpret_cast<short4v*>(&OUT[(size_t)(n0 + nr) * HID + kcol]) = o;
    }
  } else {
    const int gid = (bid - 1536) * 256 + tid;      // 0..1048575
    const int row = gid >> 7, kc = (gid & 127) << 3;
    const f32x4 a = *reinterpret_cast<const f32x4*>(&X[(size_t)row * HID + kc]);
    const f32x4 b = *reinterpret_cast<const f32x4*>(&X[(size_t)row * HID + kc + 4]);
    short8 s;
    #pragma unroll
    for (int j = 0; j < 4; j++) { s[j] = f2bs(a[j]); s[4 + j] = f2bs(b[j]); }
    const int phys = (kc & ~63) | ((kc & 63) ^ ((row & 7) << 3));
    *reinterpret_cast<short8*>(&XB[(size_t)row * HID + phys]) = s;
  }
}

// ---------------- gated GEMM: z=0 -> qg, z=1 -> kg --------------------------
// BM=256 BN=128 BK=64, 512 thr (8 waves, 4M x 2N), dual-B, XCD swizzle.
// Counted vmcnt (never 0): issues A(t+1)@P1, B1/B2(t+1)@P2;
// waits: end-P1 vmcnt(4) [guards B2(t)], end-P4 vmcnt(2) [guards A,B1(t+1)].
__global__ __launch_bounds__(512, 2) void gated8_kernel(
    const short* __restrict__ XB, const short* __restrict__ WTbase,
    const float* __restrict__ bq, const float* __restrict__ bqr,
    const float* __restrict__ bk, const float* __restrict__ bkr,
    const float* __restrict__ MASK,
    __hip_bfloat16* __restrict__ qg, __hip_bfloat16* __restrict__ kg)
{
  __shared__ short lA[2][256][64];    // 64 KB
  __shared__ short lB1[2][128][64];   // 32 KB
  __shared__ short lB2[2][128][64];   // 32 KB

  // XCD-aware bijective swizzle: 512 wg = 8 XCD x 64. Same-XCD blocks share
  // a (by,z) pair -> B panels L2-resident per XCD.
  const int d = blockIdx.x;
  const int li = (d & 7) * 64 + (d >> 3);
  const int bx = li & 31, byz = li >> 5;
  const int by = byz & 7, z = byz >> 3;

  const short* W1T = WTbase + (size_t)(2 * z) * WT_ELEMS;
  const short* W2T = W1T + WT_ELEMS;
  const float* B1b = z ? bk : bq;
  const float* B2b = z ? bkr : bqr;
  __hip_bfloat16* OUT = z ? kg : qg;

  const int m0 = bx * 256, n0 = by * 128;
  const int tid = threadIdx.x, lane = tid & 63, w = tid >> 6;
  const int wr = (w >> 1) * 64, wc = (w & 1) * 64;
  const int lrow = lane & 15, lkhi = (lane >> 4) << 3;
  const int swz = (lrow & 7) << 3;
  const int srow = lane >> 3, scol = (lane & 7) << 3;

  f32x4 acc1[4][4] = {}, acc2[4][4] = {};
  short8 bf1k[4], bf2k[4];
  short8 af0, af1, af2, af3;

  auto stA2 = [&](int slot, int kt, int i0) {   // 2 A-issues
    const int k0 = kt * 64;
    #pragma unroll
    for (int i = 0; i < 2; i++) {
      const int chunk = w * 4 + i0 + i;
      gload16(&XB[(size_t)(m0 + chunk * 8 + srow) * HID + k0 + scol],
              &lA[slot][chunk * 8][0]);
    }
  };
  auto stB1s = [&](int slot, int kt) {          // 2 B1-issues
    const int k0 = kt * 64;
    #pragma unroll
    for (int i = 0; i < 2; i++) {
      const int chunk = w * 2 + i;
      gload16(&W1T[(size_t)(n0 + chunk * 8 + srow) * HID + k0 + scol],
              &lB1[slot][chunk * 8][0]);
    }
  };
  auto stB2s = [&](int slot, int kt) {          // 2 B2-issues
    const int k0 = kt * 64;
    #pragma unroll
    for (int i = 0; i < 2; i++) {
      const int chunk = w * 2 + i;
      gload16(&W2T[(size_t)(n0 + chunk * 8 + srow) * HID + k0 + scol],
              &lB2[slot][chunk * 8][0]);
    }
  };
  auto rdA = [&](int s, int m, int kk) -> short8 {
    const int lk = (kk * 32 + lkhi) ^ swz;
    return *reinterpret_cast<const short8*>(&lA[s][wr + m * 16 + lrow][lk]);
  };

#define RDB1(S, KK)                                                                   \
  _Pragma("unroll")                                                                   \
  for (int n = 0; n < 4; n++) {                                                       \
    const int lk = ((KK) * 32 + lkhi) ^ swz;                                          \
    bf1k[n] = *reinterpret_cast<const short8*>(&lB1[S][wc + n * 16 + lrow][lk]);      \
  }
#define RDB2(S, KK)                                                                   \
  _Pragma("unroll")                                                                   \
  for (int n = 0; n < 4; n++) {                                                       \
    const int lk = ((KK) * 32 + lkhi) ^ swz;                                          \
    bf2k[n] = *reinterpret_cast<const short8*>(&lB2[S][wc + n * 16 + lrow][lk]);      \
  }
#define MM16A                                                             \
  _Pragma("unroll")                                                       \
  for (int n = 0; n < 4; n++) {                                           \
    acc1[0][n] = MFMA16x16(af0, bf1k[n], acc1[0][n], 0, 0, 0);            \
    acc1[1][n] = MFMA16x16(af1, bf1k[n], acc1[1][n], 0, 0, 0);            \
    acc1[2][n] = MFMA16x16(af2, bf1k[n], acc1[2][n], 0, 0, 0);            \
    acc1[3][n] = MFMA16x16(af3, bf1k[n], acc1[3][n], 0, 0, 0);            \
  }
#define MM16B                                                             \
  _Pragma("unroll")                                                       \
  for (int n = 0; n < 4; n++) {                                           \
    acc2[0][n] = MFMA16x16(af0, bf2k[n], acc2[0][n], 0, 0, 0);            \
    acc2[1][n] = MFMA16x16(af1, bf2k[n], acc2[1][n], 0, 0, 0);            \
    acc2[2][n] = MFMA16x16(af2, bf2k[n], acc2[2][n], 0, 0, 0);            \
    acc2[3][n] = MFMA16x16(af3, bf2k[n], acc2[3][n], 0, 0, 0);            \
  }
// Ledger per tile t (per-wave issues, FIFO): A(t):4 @t-1P1, B1/B2(t):4 @t-1P2.
// P1 reads A+B1(t): guarded by prev end-P4 vmcnt(2)+BAR.
// P2 reads B2(t):   guarded by end-P1 vmcnt(4)+BAR (leaves A(t+1) only).
#define GTILE(S, SN, TS)                                                 \
  /* P1 */                                                               \
  af0 = rdA(S, 0, 0); af1 = rdA(S, 1, 0);                                \
  af2 = rdA(S, 2, 0); af3 = rdA(S, 3, 0);                                \
  RDB1(S, 0);                                                            \
  stA2(SN, TS, 0); stA2(SN, TS, 2);                                      \
  BAR(); LGKM0;                                                          \
  PRIO1; MM16A PRIO0; SCB;                                               \
  VMWAIT(4);                                                             \
  BAR();                                                                 \
  /* P2 */                                                               \
  RDB2(S, 0);                                                            \
  stB1s(SN, TS); stB2s(SN, TS);                                          \
  BAR(); LGKM0;                                                          \
  PRIO1; MM16B PRIO0; SCB;                                               \
  BAR();                                                                 \
  /* P3 */                                                               \
  af0 = rdA(S, 0, 1); af1 = rdA(S, 1, 1);                                \
  af2 = rdA(S, 2, 1); af3 = rdA(S, 3, 1);                                \
  RDB1(S, 1);                                                            \
  BAR(); LGKM0;                                                          \
  PRIO1; MM16A PRIO0; SCB;                                               \
  BAR();                                                                 \
  /* P4 */                                                               \
  RDB2(S, 1);                                                            \
  BAR(); LGKM0;                                                          \
  PRIO1; MM16B PRIO0; SCB;                                               \
  VMWAIT(2);                                                             \
  BAR();

  // prologue: stage tile 0 into slot 0 (8 issues); need first 6 -> vmcnt(2)
  stA2(0, 0, 0); stA2(0, 0, 2); stB1s(0, 0); stB2s(0, 0);
  VMWAIT(2);
  BAR();

  #pragma unroll 1
  for (int i = 0; i < 16; i++) {
    const int S = i & 1, SN = S ^ 1;
    const int TS = (i < 15) ? i + 1 : 15;   // last iter: harmless restage
    GTILE(S, SN, TS)
  }
  VMWAIT(0);
#undef GTILE
#undef MM16A
#undef MM16B
#undef RDB1
#undef RDB2

  // epilogue: bias + reasoning-mask blend; C/D: col=lane&15, row=(lane>>4)*4+r
  #pragma unroll
  for (int m = 0; m < 4; m++) {
    const int rbase = m0 + wr + m * 16 + ((lane >> 4) << 2);
    #pragma unroll
    for (int n = 0; n < 4; n++) {
      const int col = n0 + wc + n * 16 + lrow;
      const float bias1 = B1b[col];
      const float bias2 = B2b[col];
      #pragma unroll
      for (int r = 0; r < 4; r++) {
        const int row = rbase + r;
        const float mk = MASK[row];
        const float val = (acc1[m][n][r] + bias1) * (1.f - mk) +
                          (acc2[m][n][r] + bias2) * mk;
        OUT[(size_t)row * HID + col] = __float2bfloat16(val);
      }
    }
  }
}

// ---------------- plain GEMM (single B): V-proj and out-proj ----------------
// BM=256 BN=128 BK=64, 512 thr. TRIPLE-buffered LDS (144KB): stage tile t+2
// while computing t -> vmcnt(6) once per K-tile, never 0, 4 phases of slack.
template<bool OUTF32>
__global__ __launch_bounds__(512, 2) void plain8_kernel(
    const short* __restrict__ A, const short* __restrict__ WT,
    const float* __restrict__ BIAS, void* __restrict__ OUTv)
{
  __shared__ short lA[3][256][64];    // 96 KB
  __shared__ short lB[3][128][64];    // 48 KB

  // XCD swizzle: 256 wg = 8 XCD x 32; each XCD owns one by (one B panel).
  const int d = blockIdx.x;
  const int li = (d & 7) * 32 + (d >> 3);
  const int bx = li & 31, by = li >> 5;

  const int m0 = bx * 256, n0 = by * 128;
  const int tid = threadIdx.x, lane = tid & 63, w = tid >> 6;
  const int wr = (w >> 1) * 64, wc = (w & 1) * 64;
  const int lrow = lane & 15, lkhi = (lane >> 4) << 3;
  const int swz = (lrow & 7) << 3;
  const int srow = lane >> 3, scol = (lane & 7) << 3;

  f32x4 acc[4][4] = {};
  short8 paf[4], pbf[4];

  auto stTrip = [&](int slot, int kt, int t) {  // t=0 -> A{0,1,2}; t=1 -> A3,B0,B1
    const int k0 = kt * 64;
    if (t == 0) {
      #pragma unroll
      for (int i = 0; i < 3; i++) {
        const int chunk = w * 4 + i;
        gload16(&A[(size_t)(m0 + chunk * 8 + srow) * HID + k0 + scol],
                &lA[slot][chunk * 8][0]);
      }
    } else {
      const int chunk = w * 4 + 3;
      gload16(&A[(size_t)(m0 + chunk * 8 + srow) * HID + k0 + scol],
              &lA[slot][chunk * 8][0]);
      #pragma unroll
      for (int i = 0; i < 2; i++) {
        const int bchunk = w * 2 + i;
        gload16(&WT[(size_t)(n0 + bchunk * 8 + srow) * HID + k0 + scol],
                &lB[slot][bchunk * 8][0]);
      }
    }
  };

#define RDP(S, KK)                                                                    \
  _Pragma("unroll")                                                                   \
  for (int m = 0; m < 4; m++) {                                                       \
    const int lk = ((KK) * 32 + lkhi) ^ swz;                                          \
    paf[m] = *reinterpret_cast<const short8*>(&lA[S][wr + m * 16 + lrow][lk]);        \
    pbf[m] = *reinterpret_cast<const short8*>(&lB[S][wc + m * 16 + lrow][lk]);        \
  }
#define PMM16                                                                         \
  _Pragma("unroll")                                                                   \
  for (int m = 0; m < 4; m++)                                                         \
    _Pragma("unroll")                                                                 \
    for (int n = 0; n < 4; n++)                                                       \
      acc[m][n] = MFMA16x16(paf[m], pbf[n], acc[m][n], 0, 0, 0);

  // prologue: tiles 0,1 into slots 0,1 (12 issues); need tile0 -> vmcnt(6)
  stTrip(0, 0, 0); stTrip(0, 0, 1);
  stTrip(1, 1, 0); stTrip(1, 1, 1);
  VMWAIT(6);
  BAR();

  int s = 0, s2 = 2;
  #pragma unroll 1
  for (int t = 0; t < 16; t++) {
    const int TS = (t < 14) ? t + 2 : 15;   // tail: harmless restage
    // P1
    RDP(s, 0)
    stTrip(s2, TS, 0);
    BAR(); LGKM0;
    PRIO1; PMM16 PRIO0; SCB;
    BAR();
    // P2
    RDP(s, 1)
    stTrip(s2, TS, 1);
    BAR(); LGKM0;
    PRIO1; PMM16 PRIO0; SCB;
    VMWAIT(6);     // guards tile t+1 (6 issues of t+2 in flight), never 0
    BAR();
    s = (s == 2) ? 0 : s + 1;
    s2 = (s2 == 2) ? 0 : s2 + 1;
  }
  VMWAIT(0);
#undef PMM16
#undef RDP

  #pragma unroll
  for (int m = 0; m < 4; m++) {
    const int rbase = m0 + wr + m * 16 + ((lane >> 4) << 2);
    #pragma unroll
    for (int n = 0; n < 4; n++) {
      const int col = n0 + wc + n * 16 + lrow;
      const float bias = BIAS[col];
      #pragma unroll
      for (int r = 0; r < 4; r++) {
        const float val = acc[m][n][r] + bias;
        const size_t oidx = (size_t)(rbase + r) * HID + col;
        if (OUTF32) ((float*)OUTv)[oidx] = val;
        else ((__hip_bfloat16*)OUTv)[oidx] = __float2bfloat16(val);
      }
    }
  }
}

// ---------------- per-token 16x16 cross-head attention ----------------------
// out row = b*2048 + h*128 + s/16, col = (s%16)*64 + d, stored with the
// 64-block swizzle (d ^= (row&7)<<3) so the final GEMM can global_load_lds it.
__global__ __launch_bounds__(256) void attn_kernel(
    const __hip_bfloat16* __restrict__ Q, const __hip_bfloat16* __restrict__ K,
    const __hip_bfloat16* __restrict__ V, __hip_bfloat16* __restrict__ O)
{
  const int t = blockIdx.x;
  const int b = t >> 11, s = t & 2047;
  __shared__ float sQ[16][68], sK[16][68], sV[16][68];
  __shared__ float sA[16][17];
  const int tid = threadIdx.x;
  const size_t tb = (size_t)t * HID;

  {
    const int h = tid >> 4, d0 = (tid & 15) << 2;
    const int o = (h << 6) + d0;
    const short4v qv = *reinterpret_cast<const short4v*>(&((const short*)Q)[tb + o]);
    const short4v kv = *reinterpret_cast<const short4v*>(&((const short*)K)[tb + o]);
    const short4v vv = *reinterpret_cast<const short4v*>(&((const short*)V)[tb + o]);
    #pragma unroll
    for (int j = 0; j < 4; j++) {
      sQ[h][d0 + j] = bs2f(qv[j]);
      sK[h][d0 + j] = bs2f(kv[j]);
      sV[h][d0 + j] = bs2f(vv[j]);
    }
  }
  __syncthreads();

  const int h = tid >> 4, e = tid & 15;
  float sc = 0.f;
  #pragma unroll
  for (int dd = 0; dd < 64; dd++) sc += sQ[h][dd] * sK[e][dd];
  sc *= 0.125f;

  float mx = sc;
  mx = fmaxf(mx, __shfl_xor(mx, 1));
  mx = fmaxf(mx, __shfl_xor(mx, 2));
  mx = fmaxf(mx, __shfl_xor(mx, 4));
  mx = fmaxf(mx, __shfl_xor(mx, 8));
  const float p = __expf(sc - mx);
  float sm = p;
  sm += __shfl_xor(sm, 1);
  sm += __shfl_xor(sm, 2);
  sm += __shfl_xor(sm, 4);
  sm += __shfl_xor(sm, 8);
  sA[h][e] = p / sm;
  __syncthreads();

  const int row7 = (s >> 4) & 7;
  const size_t ob = ((size_t)b * 2048 + (s >> 4)) * HID + ((size_t)(s & 15) << 6);
  {
    const int hh = tid >> 4, d4 = (tid & 15) << 2;
    f32x4 o = {0.f, 0.f, 0.f, 0.f};
    #pragma unroll
    for (int e2 = 0; e2 < 16; e2++) {
      const float a = sA[hh][e2];
      #pragma unroll
      for (int j = 0; j < 4; j++) o[j] += a * sV[e2][d4 + j];
    }
    short4v ov;
    #pragma unroll
    for (int j = 0; j < 4; j++) ov[j] = f2bs(o[j]);
    *reinterpret_cast<short4v*>(
        &((short*)O)[ob + (size_t)hh * 128 * HID + (d4 ^ (row7 << 3))]) = ov;
  }
}

extern "C" void kernel_launch(void* const* d_in, const int* in_sizes, int n_in,
                              void* d_out, int out_size, void* d_ws, size_t ws_size,
                              hipStream_t stream) {
  (void)in_sizes; (void)n_in; (void)out_size; (void)ws_size;
  const float* x   = (const float*)d_in[0];
  const float* rm  = (const float*)d_in[1];
  const float* Wq  = (const float*)d_in[2];
  const float* bq  = (const float*)d_in[3];
  const float* Wk  = (const float*)d_in[4];
  const float* bk  = (const float*)d_in[5];
  const float* Wv  = (const float*)d_in[6];
  const float* bv  = (const float*)d_in[7];
  const float* Wqr = (const float*)d_in[8];
  const float* bqr = (const float*)d_in[9];
  const float* Wkr = (const float*)d_in[10];
  const float* bkr = (const float*)d_in[11];
  const float* Wo  = (const float*)d_in[12];
  const float* bo  = (const float*)d_in[13];

  // ws: [0:12M) WT (Wq,Wqr,Wk,Wkr,Wv,Wo) | [12:28M) qg | [28:44M) vv | [44:60M) ar
  char* ws = (char*)d_ws;
  short* wt = (short*)ws;
  __hip_bfloat16* qg = (__hip_bfloat16*)(ws + 12u * 1024 * 1024);
  __hip_bfloat16* vv = (__hip_bfloat16*)(ws + 28u * 1024 * 1024);
  __hip_bfloat16* ar = (__hip_bfloat16*)(ws + 44u * 1024 * 1024);
  // d_out (32 MiB fp32) doubles as scratch until the final GEMM rewrites it:
  short* xb = (short*)d_out;                                        // [0:16M)
  __hip_bfloat16* kg = (__hip_bfloat16*)((char*)d_out + 16u * 1024 * 1024);  // [16:32M)

  prep_kernel<<<dim3(5632), 256, 0, stream>>>(Wq, Wqr, Wk, Wkr, Wv, Wo, x, wt, xb);
  gated8_kernel<<<dim3(512), 512, 0, stream>>>(xb, wt, bq, bqr, bk, bkr, rm, qg, kg);
  plain8_kernel<false><<<dim3(256), 512, 0, stream>>>(xb, wt + (size_t)4 * WT_ELEMS, bv, vv);
  attn_kernel<<<dim3(NTOK), 256, 0, stream>>>(qg, kg, vv, ar);
  plain8_kernel<true><<<dim3(256), 512, 0, stream>>>((const short*)ar,
                                                     wt + (size_t)5 * WT_ELEMS, bo, d_out);
}

// Round 8
// 147.744 us; speedup vs baseline: 1.1322x; 1.1322x over previous
//
#include <hip/hip_runtime.h>
#include <hip/hip_bf16.h>

// ReasoningMultiHeadAttention: B=4 S=2048 HID=1024 NH=16 DH=64. All I/O fp32.
// prep: 6x W -> bf16 W^T pre-swizzled (wt, ws) ; x -> bf16 xb pre-swizzled (in d_out!)
// gated8: dual-B GEMM, 4 phases/K-tile, counted vmcnt(4)/(2) NEVER 0, LINEAR block map
// plain8<bf16>: xb @ WvT + bv -> vv ; TRIPLE-buffered LDS, vmcnt(6) never 0
// attn: per-token 16x16 cross-head attn -> ar (ws, swizzled+scrambled)
// plain8<f32>: ar @ WoT + bo -> d_out (overwrites xb/kg scratch, all dead)
// ws usage: [0:12M wt][12:28M qg][28:44M vv][44:60M ar] = 60 MB
// d_out scratch: [0:16M xb][16:32M kg] until final GEMM rewrites all of d_out.
// R8: XCD swizzle REVERTED (R7 post-mortem: it forced every XCD to stream all
// of A -> FETCH 49->135MB). Linear map keeps A-panel/XCD affinity (bx%8).

typedef __attribute__((ext_vector_type(8))) short short8;
typedef __attribute__((ext_vector_type(4))) short short4v;
typedef __attribute__((ext_vector_type(4))) float f32x4;

#define HID 1024
#define NTOK 8192
#define WT_ELEMS (1024 * 1024)

__device__ __forceinline__ short f2bs(float f) {
  __hip_bfloat16 h = __float2bfloat16(f);
  return *reinterpret_cast<short*>(&h);
}
__device__ __forceinline__ float bs2f(short s) {
  __hip_bfloat16 h;
  *reinterpret_cast<short*>(&h) = s;
  return __bfloat162float(h);
}
__device__ __forceinline__ void gload16(const void* g, void* l) {
  __builtin_amdgcn_global_load_lds(
      (const __attribute__((address_space(1))) void*)g,
      (__attribute__((address_space(3))) void*)l, 16, 0, 0);
}

#define BAR() asm volatile("s_barrier" ::: "memory")
#define VMWAIT(N) asm volatile("s_waitcnt vmcnt(" #N ")" ::: "memory")
#define LGKM0 do { asm volatile("s_waitcnt lgkmcnt(0)" ::: "memory"); \
                   __builtin_amdgcn_sched_barrier(0); } while (0)
#define SCB __builtin_amdgcn_sched_barrier(0)
#define PRIO1 __builtin_amdgcn_s_setprio(1)
#define PRIO0 __builtin_amdgcn_s_setprio(0)
#define MFMA16x16 __builtin_amdgcn_mfma_f32_16x16x32_bf16

// ---------------- prep: W transposes (z<6) + x fp32->bf16 convert ----------
// WT[n][ (k&~63) | ((k&63) ^ ((n&7)<<3)) ] = bf16(W[k][n])
// XB[row][ (k&~63) | ((k&63) ^ ((row&7)<<3)) ] = bf16(x[row][k])
__global__ __launch_bounds__(256) void prep_kernel(
    const float* __restrict__ W0, const float* __restrict__ W1,
    const float* __restrict__ W2, const float* __restrict__ W3,
    const float* __restrict__ W4, const float* __restrict__ W5,
    const float* __restrict__ X, short* __restrict__ WT, short* __restrict__ XB)
{
  __shared__ short sT[64][68];
  const int bid = blockIdx.x, tid = threadIdx.x;
  if (bid < 1536) {
    const int z = bid >> 8, rem = bid & 255;
    const float* W = z == 0 ? W0 : z == 1 ? W1 : z == 2 ? W2 : z == 3 ? W3
                   : z == 4 ? W4 : W5;
    short* OUT = WT + (size_t)z * WT_ELEMS;
    const int k0 = (rem & 15) * 64, n0 = (rem >> 4) * 64;
    #pragma unroll
    for (int i = 0; i < 4; i++) {
      const int li = tid + i * 256;
      const int kr = li >> 4, c4 = (li & 15) << 2;
      const f32x4 wv = *reinterpret_cast<const f32x4*>(&W[(size_t)(k0 + kr) * HID + n0 + c4]);
      short4v s4;
      #pragma unroll
      for (int j = 0; j < 4; j++) s4[j] = f2bs(wv[j]);
      *reinterpret_cast<short4v*>(&sT[kr][c4]) = s4;
    }
    __syncthreads();
    #pragma unroll
    for (int i = 0; i < 4; i++) {
      const int li = tid + i * 256;
      const int nr = li >> 4, k4 = (li & 15) << 2;
      short4v o;
      #pragma unroll
      for (int j = 0; j < 4; j++) o[j] = sT[k4 + j][nr];
      const int kcol = (k0 + k4) ^ ((nr & 7) << 3);
      *reinterpret_cast<short4v*>(&OUT[(size_t)(n0 + nr) * HID + kcol]) = o;
    }
  } else {
    const int gid = (bid - 1536) * 256 + tid;      // 0..1048575
    const int row = gid >> 7, kc = (gid & 127) << 3;
    const f32x4 a = *reinterpret_cast<const f32x4*>(&X[(size_t)row * HID + kc]);
    const f32x4 b = *reinterpret_cast<const f32x4*>(&X[(size_t)row * HID + kc + 4]);
    short8 s;
    #pragma unroll
    for (int j = 0; j < 4; j++) { s[j] = f2bs(a[j]); s[4 + j] = f2bs(b[j]); }
    const int phys = (kc & ~63) | ((kc & 63) ^ ((row & 7) << 3));
    *reinterpret_cast<short8*>(&XB[(size_t)row * HID + phys]) = s;
  }
}

// ---------------- gated GEMM: z=0 -> qg, z=1 -> kg --------------------------
// BM=256 BN=128 BK=64, 512 thr (8 waves, 4M x 2N), dual-B, LINEAR block map.
// Counted vmcnt (never 0): issues A(t+1)@P1, B1/B2(t+1)@P2;
// waits: end-P1 vmcnt(4) [guards B2(t)], end-P4 vmcnt(2) [guards A,B1(t+1)].
__global__ __launch_bounds__(512, 2) void gated8_kernel(
    const short* __restrict__ XB, const short* __restrict__ WTbase,
    const float* __restrict__ bq, const float* __restrict__ bqr,
    const float* __restrict__ bk, const float* __restrict__ bkr,
    const float* __restrict__ MASK,
    __hip_bfloat16* __restrict__ qg, __hip_bfloat16* __restrict__ kg)
{
  __shared__ short lA[2][256][64];    // 64 KB
  __shared__ short lB1[2][128][64];   // 32 KB
  __shared__ short lB2[2][128][64];   // 32 KB

  // linear map (== dispatch order): XCD gets bx%8 stripes -> A panels L2-local
  const int d = blockIdx.x;
  const int bx = d & 31, byz = d >> 5;
  const int by = byz & 7, z = byz >> 3;

  const short* W1T = WTbase + (size_t)(2 * z) * WT_ELEMS;
  const short* W2T = W1T + WT_ELEMS;
  const float* B1b = z ? bk : bq;
  const float* B2b = z ? bkr : bqr;
  __hip_bfloat16* OUT = z ? kg : qg;

  const int m0 = bx * 256, n0 = by * 128;
  const int tid = threadIdx.x, lane = tid & 63, w = tid >> 6;
  const int wr = (w >> 1) * 64, wc = (w & 1) * 64;
  const int lrow = lane & 15, lkhi = (lane >> 4) << 3;
  const int swz = (lrow & 7) << 3;
  const int srow = lane >> 3, scol = (lane & 7) << 3;

  f32x4 acc1[4][4] = {}, acc2[4][4] = {};
  short8 bf1k[4], bf2k[4];
  short8 af0, af1, af2, af3;

  auto stA2 = [&](int slot, int kt, int i0) {   // 2 A-issues
    const int k0 = kt * 64;
    #pragma unroll
    for (int i = 0; i < 2; i++) {
      const int chunk = w * 4 + i0 + i;
      gload16(&XB[(size_t)(m0 + chunk * 8 + srow) * HID + k0 + scol],
              &lA[slot][chunk * 8][0]);
    }
  };
  auto stB1s = [&](int slot, int kt) {          // 2 B1-issues
    const int k0 = kt * 64;
    #pragma unroll
    for (int i = 0; i < 2; i++) {
      const int chunk = w * 2 + i;
      gload16(&W1T[(size_t)(n0 + chunk * 8 + srow) * HID + k0 + scol],
              &lB1[slot][chunk * 8][0]);
    }
  };
  auto stB2s = [&](int slot, int kt) {          // 2 B2-issues
    const int k0 = kt * 64;
    #pragma unroll
    for (int i = 0; i < 2; i++) {
      const int chunk = w * 2 + i;
      gload16(&W2T[(size_t)(n0 + chunk * 8 + srow) * HID + k0 + scol],
              &lB2[slot][chunk * 8][0]);
    }
  };
  auto rdA = [&](int s, int m, int kk) -> short8 {
    const int lk = (kk * 32 + lkhi) ^ swz;
    return *reinterpret_cast<const short8*>(&lA[s][wr + m * 16 + lrow][lk]);
  };

#define RDB1(S, KK)                                                                   \
  _Pragma("unroll")                                                                   \
  for (int n = 0; n < 4; n++) {                                                       \
    const int lk = ((KK) * 32 + lkhi) ^ swz;                                          \
    bf1k[n] = *reinterpret_cast<const short8*>(&lB1[S][wc + n * 16 + lrow][lk]);      \
  }
#define RDB2(S, KK)                                                                   \
  _Pragma("unroll")                                                                   \
  for (int n = 0; n < 4; n++) {                                                       \
    const int lk = ((KK) * 32 + lkhi) ^ swz;                                          \
    bf2k[n] = *reinterpret_cast<const short8*>(&lB2[S][wc + n * 16 + lrow][lk]);      \
  }
#define MM16A                                                             \
  _Pragma("unroll")                                                       \
  for (int n = 0; n < 4; n++) {                                           \
    acc1[0][n] = MFMA16x16(af0, bf1k[n], acc1[0][n], 0, 0, 0);            \
    acc1[1][n] = MFMA16x16(af1, bf1k[n], acc1[1][n], 0, 0, 0);            \
    acc1[2][n] = MFMA16x16(af2, bf1k[n], acc1[2][n], 0, 0, 0);            \
    acc1[3][n] = MFMA16x16(af3, bf1k[n], acc1[3][n], 0, 0, 0);            \
  }
#define MM16B                                                             \
  _Pragma("unroll")                                                       \
  for (int n = 0; n < 4; n++) {                                           \
    acc2[0][n] = MFMA16x16(af0, bf2k[n], acc2[0][n], 0, 0, 0);            \
    acc2[1][n] = MFMA16x16(af1, bf2k[n], acc2[1][n], 0, 0, 0);            \
    acc2[2][n] = MFMA16x16(af2, bf2k[n], acc2[2][n], 0, 0, 0);            \
    acc2[3][n] = MFMA16x16(af3, bf2k[n], acc2[3][n], 0, 0, 0);            \
  }
// Ledger per tile t (per-wave issues, FIFO): A(t):4 @t-1P1, B1/B2(t):4 @t-1P2.
// P1 reads A+B1(t): guarded by prev end-P4 vmcnt(2)+BAR.
// P2 reads B2(t):   guarded by end-P1 vmcnt(4)+BAR (leaves A(t+1) only).
#define GTILE(S, SN, TS)                                                 \
  /* P1 */                                                               \
  af0 = rdA(S, 0, 0); af1 = rdA(S, 1, 0);                                \
  af2 = rdA(S, 2, 0); af3 = rdA(S, 3, 0);                                \
  RDB1(S, 0);                                                            \
  stA2(SN, TS, 0); stA2(SN, TS, 2);                                      \
  BAR(); LGKM0;                                                          \
  PRIO1; MM16A PRIO0; SCB;                                               \
  VMWAIT(4);                                                             \
  BAR();                                                                 \
  /* P2 */                                                               \
  RDB2(S, 0);                                                            \
  stB1s(SN, TS); stB2s(SN, TS);                                          \
  BAR(); LGKM0;                                                          \
  PRIO1; MM16B PRIO0; SCB;                                               \
  BAR();                                                                 \
  /* P3 */                                                               \
  af0 = rdA(S, 0, 1); af1 = rdA(S, 1, 1);                                \
  af2 = rdA(S, 2, 1); af3 = rdA(S, 3, 1);                                \
  RDB1(S, 1);                                                            \
  BAR(); LGKM0;                                                          \
  PRIO1; MM16A PRIO0; SCB;                                               \
  BAR();                                                                 \
  /* P4 */                                                               \
  RDB2(S, 1);                                                            \
  BAR(); LGKM0;                                                          \
  PRIO1; MM16B PRIO0; SCB;                                               \
  VMWAIT(2);                                                             \
  BAR();

  // prologue: stage tile 0 into slot 0 (8 issues); need first 6 -> vmcnt(2)
  stA2(0, 0, 0); stA2(0, 0, 2); stB1s(0, 0); stB2s(0, 0);
  VMWAIT(2);
  BAR();

  #pragma unroll 1
  for (int i = 0; i < 16; i++) {
    const int S = i & 1, SN = S ^ 1;
    const int TS = (i < 15) ? i + 1 : 15;   // last iter: harmless restage
    GTILE(S, SN, TS)
  }
  VMWAIT(0);
#undef GTILE
#undef MM16A
#undef MM16B
#undef RDB1
#undef RDB2

  // epilogue: bias + reasoning-mask blend; C/D: col=lane&15, row=(lane>>4)*4+r
  #pragma unroll
  for (int m = 0; m < 4; m++) {
    const int rbase = m0 + wr + m * 16 + ((lane >> 4) << 2);
    #pragma unroll
    for (int n = 0; n < 4; n++) {
      const int col = n0 + wc + n * 16 + lrow;
      const float bias1 = B1b[col];
      const float bias2 = B2b[col];
      #pragma unroll
      for (int r = 0; r < 4; r++) {
        const int row = rbase + r;
        const float mk = MASK[row];
        const float val = (acc1[m][n][r] + bias1) * (1.f - mk) +
                          (acc2[m][n][r] + bias2) * mk;
        OUT[(size_t)row * HID + col] = __float2bfloat16(val);
      }
    }
  }
}

// ---------------- plain GEMM (single B): V-proj and out-proj ----------------
// BM=256 BN=128 BK=64, 512 thr. TRIPLE-buffered LDS (144KB): stage tile t+2
// while computing t -> vmcnt(6) once per K-tile, never 0, 4 phases of slack.
template<bool OUTF32>
__global__ __launch_bounds__(512, 2) void plain8_kernel(
    const short* __restrict__ A, const short* __restrict__ WT,
    const float* __restrict__ BIAS, void* __restrict__ OUTv)
{
  __shared__ short lA[3][256][64];    // 96 KB
  __shared__ short lB[3][128][64];    // 48 KB

  // linear map (== dispatch order)
  const int d = blockIdx.x;
  const int bx = d & 31, by = d >> 5;

  const int m0 = bx * 256, n0 = by * 128;
  const int tid = threadIdx.x, lane = tid & 63, w = tid >> 6;
  const int wr = (w >> 1) * 64, wc = (w & 1) * 64;
  const int lrow = lane & 15, lkhi = (lane >> 4) << 3;
  const int swz = (lrow & 7) << 3;
  const int srow = lane >> 3, scol = (lane & 7) << 3;

  f32x4 acc[4][4] = {};
  short8 paf[4], pbf[4];

  auto stTrip = [&](int slot, int kt, int t) {  // t=0 -> A{0,1,2}; t=1 -> A3,B0,B1
    const int k0 = kt * 64;
    if (t == 0) {
      #pragma unroll
      for (int i = 0; i < 3; i++) {
        const int chunk = w * 4 + i;
        gload16(&A[(size_t)(m0 + chunk * 8 + srow) * HID + k0 + scol],
                &lA[slot][chunk * 8][0]);
      }
    } else {
      const int chunk = w * 4 + 3;
      gload16(&A[(size_t)(m0 + chunk * 8 + srow) * HID + k0 + scol],
              &lA[slot][chunk * 8][0]);
      #pragma unroll
      for (int i = 0; i < 2; i++) {
        const int bchunk = w * 2 + i;
        gload16(&WT[(size_t)(n0 + bchunk * 8 + srow) * HID + k0 + scol],
                &lB[slot][bchunk * 8][0]);
      }
    }
  };

#define RDP(S, KK)                                                                    \
  _Pragma("unroll")                                                                   \
  for (int m = 0; m < 4; m++) {                                                       \
    const int lk = ((KK) * 32 + lkhi) ^ swz;                                          \
    paf[m] = *reinterpret_cast<const short8*>(&lA[S][wr + m * 16 + lrow][lk]);        \
    pbf[m] = *reinterpret_cast<const short8*>(&lB[S][wc + m * 16 + lrow][lk]);        \
  }
#define PMM16                                                                         \
  _Pragma("unroll")                                                                   \
  for (int m = 0; m < 4; m++)                                                         \
    _Pragma("unroll")                                                                 \
    for (int n = 0; n < 4; n++)                                                       \
      acc[m][n] = MFMA16x16(paf[m], pbf[n], acc[m][n], 0, 0, 0);

  // prologue: tiles 0,1 into slots 0,1 (12 issues); need tile0 -> vmcnt(6)
  stTrip(0, 0, 0); stTrip(0, 0, 1);
  stTrip(1, 1, 0); stTrip(1, 1, 1);
  VMWAIT(6);
  BAR();

  int s = 0, s2 = 2;
  #pragma unroll 1
  for (int t = 0; t < 16; t++) {
    const int TS = (t < 14) ? t + 2 : 15;   // tail: harmless restage
    // P1
    RDP(s, 0)
    stTrip(s2, TS, 0);
    BAR(); LGKM0;
    PRIO1; PMM16 PRIO0; SCB;
    BAR();
    // P2
    RDP(s, 1)
    stTrip(s2, TS, 1);
    BAR(); LGKM0;
    PRIO1; PMM16 PRIO0; SCB;
    VMWAIT(6);     // guards tile t+1 (6 issues of t+2 in flight), never 0
    BAR();
    s = (s == 2) ? 0 : s + 1;
    s2 = (s2 == 2) ? 0 : s2 + 1;
  }
  VMWAIT(0);
#undef PMM16
#undef RDP

  #pragma unroll
  for (int m = 0; m < 4; m++) {
    const int rbase = m0 + wr + m * 16 + ((lane >> 4) << 2);
    #pragma unroll
    for (int n = 0; n < 4; n++) {
      const int col = n0 + wc + n * 16 + lrow;
      const float bias = BIAS[col];
      #pragma unroll
      for (int r = 0; r < 4; r++) {
        const float val = acc[m][n][r] + bias;
        const size_t oidx = (size_t)(rbase + r) * HID + col;
        if (OUTF32) ((float*)OUTv)[oidx] = val;
        else ((__hip_bfloat16*)OUTv)[oidx] = __float2bfloat16(val);
      }
    }
  }
}

// ---------------- per-token 16x16 cross-head attention ----------------------
// out row = b*2048 + h*128 + s/16, col = (s%16)*64 + d, stored with the
// 64-block swizzle (d ^= (row&7)<<3) so the final GEMM can global_load_lds it.
__global__ __launch_bounds__(256) void attn_kernel(
    const __hip_bfloat16* __restrict__ Q, const __hip_bfloat16* __restrict__ K,
    const __hip_bfloat16* __restrict__ V, __hip_bfloat16* __restrict__ O)
{
  const int t = blockIdx.x;
  const int b = t >> 11, s = t & 2047;
  __shared__ float sQ[16][68], sK[16][68], sV[16][68];
  __shared__ float sA[16][17];
  const int tid = threadIdx.x;
  const size_t tb = (size_t)t * HID;

  {
    const int h = tid >> 4, d0 = (tid & 15) << 2;
    const int o = (h << 6) + d0;
    const short4v qv = *reinterpret_cast<const short4v*>(&((const short*)Q)[tb + o]);
    const short4v kv = *reinterpret_cast<const short4v*>(&((const short*)K)[tb + o]);
    const short4v vv = *reinterpret_cast<const short4v*>(&((const short*)V)[tb + o]);
    #pragma unroll
    for (int j = 0; j < 4; j++) {
      sQ[h][d0 + j] = bs2f(qv[j]);
      sK[h][d0 + j] = bs2f(kv[j]);
      sV[h][d0 + j] = bs2f(vv[j]);
    }
  }
  __syncthreads();

  const int h = tid >> 4, e = tid & 15;
  float sc = 0.f;
  #pragma unroll
  for (int dd = 0; dd < 64; dd++) sc += sQ[h][dd] * sK[e][dd];
  sc *= 0.125f;

  float mx = sc;
  mx = fmaxf(mx, __shfl_xor(mx, 1));
  mx = fmaxf(mx, __shfl_xor(mx, 2));
  mx = fmaxf(mx, __shfl_xor(mx, 4));
  mx = fmaxf(mx, __shfl_xor(mx, 8));
  const float p = __expf(sc - mx);
  float sm = p;
  sm += __shfl_xor(sm, 1);
  sm += __shfl_xor(sm, 2);
  sm += __shfl_xor(sm, 4);
  sm += __shfl_xor(sm, 8);
  sA[h][e] = p / sm;
  __syncthreads();

  const int row7 = (s >> 4) & 7;
  const size_t ob = ((size_t)b * 2048 + (s >> 4)) * HID + ((size_t)(s & 15) << 6);
  {
    const int hh = tid >> 4, d4 = (tid & 15) << 2;
    f32x4 o = {0.f, 0.f, 0.f, 0.f};
    #pragma unroll
    for (int e2 = 0; e2 < 16; e2++) {
      const float a = sA[hh][e2];
      #pragma unroll
      for (int j = 0; j < 4; j++) o[j] += a * sV[e2][d4 + j];
    }
    short4v ov;
    #pragma unroll
    for (int j = 0; j < 4; j++) ov[j] = f2bs(o[j]);
    *reinterpret_cast<short4v*>(
        &((short*)O)[ob + (size_t)hh * 128 * HID + (d4 ^ (row7 << 3))]) = ov;
  }
}

extern "C" void kernel_launch(void* const* d_in, const int* in_sizes, int n_in,
                              void* d_out, int out_size, void* d_ws, size_t ws_size,
                              hipStream_t stream) {
  (void)in_sizes; (void)n_in; (void)out_size; (void)ws_size;
  const float* x   = (const float*)d_in[0];
  const float* rm  = (const float*)d_in[1];
  const float* Wq  = (const float*)d_in[2];
  const float* bq  = (const float*)d_in[3];
  const float* Wk  = (const float*)d_in[4];
  const float* bk  = (const float*)d_in[5];
  const float* Wv  = (const float*)d_in[6];
  const float* bv  = (const float*)d_in[7];
  const float* Wqr = (const float*)d_in[8];
  const float* bqr = (const float*)d_in[9];
  const float* Wkr = (const float*)d_in[10];
  const float* bkr = (const float*)d_in[11];
  const float* Wo  = (const float*)d_in[12];
  const float* bo  = (const float*)d_in[13];

  // ws: [0:12M) WT (Wq,Wqr,Wk,Wkr,Wv,Wo) | [12:28M) qg | [28:44M) vv | [44:60M) ar
  char* ws = (char*)d_ws;
  short* wt = (short*)ws;
  __hip_bfloat16* qg = (__hip_bfloat16*)(ws + 12u * 1024 * 1024);
  __hip_bfloat16* vv = (__hip_bfloat16*)(ws + 28u * 1024 * 1024);
  __hip_bfloat16* ar = (__hip_bfloat16*)(ws + 44u * 1024 * 1024);
  // d_out (32 MiB fp32) doubles as scratch until the final GEMM rewrites it:
  short* xb = (short*)d_out;                                        // [0:16M)
  __hip_bfloat16* kg = (__hip_bfloat16*)((char*)d_out + 16u * 1024 * 1024);  // [16:32M)

  prep_kernel<<<dim3(5632), 256, 0, stream>>>(Wq, Wqr, Wk, Wkr, Wv, Wo, x, wt, xb);
  gated8_kernel<<<dim3(512), 512, 0, stream>>>(xb, wt, bq, bqr, bk, bkr, rm, qg, kg);
  plain8_kernel<false><<<dim3(256), 512, 0, stream>>>(xb, wt + (size_t)4 * WT_ELEMS, bv, vv);
  attn_kernel<<<dim3(NTOK), 256, 0, stream>>>(qg, kg, vv, ar);
  plain8_kernel<true><<<dim3(256), 512, 0, stream>>>((const short*)ar,
                                                     wt + (size_t)5 * WT_ELEMS, bo, d_out);
}

// Round 9
// 147.141 us; speedup vs baseline: 1.1369x; 1.0041x over previous
//
#include <hip/hip_runtime.h>
#include <hip/hip_bf16.h>

// ReasoningMultiHeadAttention: B=4 S=2048 HID=1024 NH=16 DH=64. All I/O fp32.
// prep: 6x W -> bf16 W^T pre-swizzled (wt, ws) ; x -> bf16 xb pre-swizzled (in d_out!)
// gated8: dual-B GEMM, 4 phases/K-tile, counted vmcnt, WAR-free reg ping-pong (af x2)
// plain8<bf16>: xb @ WvT + bv -> vv ; triple-buffered LDS, per-kk reg sets
// attn: per-token 16x16 cross-head attn -> ar (ws, swizzled+scrambled)
// plain8<f32>: ar @ WoT + bo -> d_out (overwrites xb/kg scratch, all dead)
// ws usage: [0:12M wt][12:28M qg][28:44M vv][44:60M ar] = 60 MB
// d_out scratch: [0:16M xb][16:32M kg] until final GEMM rewrites all of d_out.
// R9: fragment-register double-buffering kills the cross-phase WAR stall
// (ds_read of phase p+1 no longer overwrites operands of phase p's queued MFMAs).

typedef __attribute__((ext_vector_type(8))) short short8;
typedef __attribute__((ext_vector_type(4))) short short4v;
typedef __attribute__((ext_vector_type(4))) float f32x4;

#define HID 1024
#define NTOK 8192
#define WT_ELEMS (1024 * 1024)

__device__ __forceinline__ short f2bs(float f) {
  __hip_bfloat16 h = __float2bfloat16(f);
  return *reinterpret_cast<short*>(&h);
}
__device__ __forceinline__ float bs2f(short s) {
  __hip_bfloat16 h;
  *reinterpret_cast<short*>(&h) = s;
  return __bfloat162float(h);
}
__device__ __forceinline__ void gload16(const void* g, void* l) {
  __builtin_amdgcn_global_load_lds(
      (const __attribute__((address_space(1))) void*)g,
      (__attribute__((address_space(3))) void*)l, 16, 0, 0);
}

#define BAR() asm volatile("s_barrier" ::: "memory")
#define VMWAIT(N) asm volatile("s_waitcnt vmcnt(" #N ")" ::: "memory")
#define LGKM0 do { asm volatile("s_waitcnt lgkmcnt(0)" ::: "memory"); \
                   __builtin_amdgcn_sched_barrier(0); } while (0)
#define SCB __builtin_amdgcn_sched_barrier(0)
#define PRIO1 __builtin_amdgcn_s_setprio(1)
#define PRIO0 __builtin_amdgcn_s_setprio(0)
#define MFMA16x16 __builtin_amdgcn_mfma_f32_16x16x32_bf16

// ---------------- prep: W transposes (z<6) + x fp32->bf16 convert ----------
// WT[n][ (k&~63) | ((k&63) ^ ((n&7)<<3)) ] = bf16(W[k][n])
// XB[row][ (k&~63) | ((k&63) ^ ((row&7)<<3)) ] = bf16(x[row][k])
__global__ __launch_bounds__(256) void prep_kernel(
    const float* __restrict__ W0, const float* __restrict__ W1,
    const float* __restrict__ W2, const float* __restrict__ W3,
    const float* __restrict__ W4, const float* __restrict__ W5,
    const float* __restrict__ X, short* __restrict__ WT, short* __restrict__ XB)
{
  __shared__ short sT[64][68];
  const int bid = blockIdx.x, tid = threadIdx.x;
  if (bid < 1536) {
    const int z = bid >> 8, rem = bid & 255;
    const float* W = z == 0 ? W0 : z == 1 ? W1 : z == 2 ? W2 : z == 3 ? W3
                   : z == 4 ? W4 : W5;
    short* OUT = WT + (size_t)z * WT_ELEMS;
    const int k0 = (rem & 15) * 64, n0 = (rem >> 4) * 64;
    #pragma unroll
    for (int i = 0; i < 4; i++) {
      const int li = tid + i * 256;
      const int kr = li >> 4, c4 = (li & 15) << 2;
      const f32x4 wv = *reinterpret_cast<const f32x4*>(&W[(size_t)(k0 + kr) * HID + n0 + c4]);
      short4v s4;
      #pragma unroll
      for (int j = 0; j < 4; j++) s4[j] = f2bs(wv[j]);
      *reinterpret_cast<short4v*>(&sT[kr][c4]) = s4;
    }
    __syncthreads();
    #pragma unroll
    for (int i = 0; i < 4; i++) {
      const int li = tid + i * 256;
      const int nr = li >> 4, k4 = (li & 15) << 2;
      short4v o;
      #pragma unroll
      for (int j = 0; j < 4; j++) o[j] = sT[k4 + j][nr];
      const int kcol = (k0 + k4) ^ ((nr & 7) << 3);
      *reinterpret_cast<short4v*>(&OUT[(size_t)(n0 + nr) * HID + kcol]) = o;
    }
  } else {
    const int gid = (bid - 1536) * 256 + tid;      // 0..1048575
    const int row = gid >> 7, kc = (gid & 127) << 3;
    const f32x4 a = *reinterpret_cast<const f32x4*>(&X[(size_t)row * HID + kc]);
    const f32x4 b = *reinterpret_cast<const f32x4*>(&X[(size_t)row * HID + kc + 4]);
    short8 s;
    #pragma unroll
    for (int j = 0; j < 4; j++) { s[j] = f2bs(a[j]); s[4 + j] = f2bs(b[j]); }
    const int phys = (kc & ~63) | ((kc & 63) ^ ((row & 7) << 3));
    *reinterpret_cast<short8*>(&XB[(size_t)row * HID + phys]) = s;
  }
}

// ---------------- gated GEMM: z=0 -> qg, z=1 -> kg --------------------------
// BM=256 BN=128 BK=64, 512 thr (8 waves, 4M x 2N), dual-B, LINEAR block map.
// Counted vmcnt (never 0) + af register ping-pong (WAR-free phase overlap).
__global__ __launch_bounds__(512, 2) void gated8_kernel(
    const short* __restrict__ XB, const short* __restrict__ WTbase,
    const float* __restrict__ bq, const float* __restrict__ bqr,
    const float* __restrict__ bk, const float* __restrict__ bkr,
    const float* __restrict__ MASK,
    __hip_bfloat16* __restrict__ qg, __hip_bfloat16* __restrict__ kg)
{
  __shared__ short lA[2][256][64];    // 64 KB
  __shared__ short lB1[2][128][64];   // 32 KB
  __shared__ short lB2[2][128][64];   // 32 KB

  // linear map (== dispatch order): XCD gets bx%8 stripes -> A panels L2-local
  const int d = blockIdx.x;
  const int bx = d & 31, byz = d >> 5;
  const int by = byz & 7, z = byz >> 3;

  const short* W1T = WTbase + (size_t)(2 * z) * WT_ELEMS;
  const short* W2T = W1T + WT_ELEMS;
  const float* B1b = z ? bk : bq;
  const float* B2b = z ? bkr : bqr;
  __hip_bfloat16* OUT = z ? kg : qg;

  const int m0 = bx * 256, n0 = by * 128;
  const int tid = threadIdx.x, lane = tid & 63, w = tid >> 6;
  const int wr = (w >> 1) * 64, wc = (w & 1) * 64;
  const int lrow = lane & 15, lkhi = (lane >> 4) << 3;
  const int swz = (lrow & 7) << 3;
  const int srow = lane >> 3, scol = (lane & 7) << 3;

  f32x4 acc1[4][4] = {}, acc2[4][4] = {};
  short8 bf1k[4], bf2k[4];
  short8 afA0, afA1, afA2, afA3;   // set A: written P1, read clusters 1-2
  short8 afB0, afB1, afB2, afB3;   // set B: written P3, read clusters 3-4

  auto stA2 = [&](int slot, int kt, int i0) {   // 2 A-issues
    const int k0 = kt * 64;
    #pragma unroll
    for (int i = 0; i < 2; i++) {
      const int chunk = w * 4 + i0 + i;
      gload16(&XB[(size_t)(m0 + chunk * 8 + srow) * HID + k0 + scol],
              &lA[slot][chunk * 8][0]);
    }
  };
  auto stB1s = [&](int slot, int kt) {          // 2 B1-issues
    const int k0 = kt * 64;
    #pragma unroll
    for (int i = 0; i < 2; i++) {
      const int chunk = w * 2 + i;
      gload16(&W1T[(size_t)(n0 + chunk * 8 + srow) * HID + k0 + scol],
              &lB1[slot][chunk * 8][0]);
    }
  };
  auto stB2s = [&](int slot, int kt) {          // 2 B2-issues
    const int k0 = kt * 64;
    #pragma unroll
    for (int i = 0; i < 2; i++) {
      const int chunk = w * 2 + i;
      gload16(&W2T[(size_t)(n0 + chunk * 8 + srow) * HID + k0 + scol],
              &lB2[slot][chunk * 8][0]);
    }
  };
  auto rdA = [&](int s, int m, int kk) -> short8 {
    const int lk = (kk * 32 + lkhi) ^ swz;
    return *reinterpret_cast<const short8*>(&lA[s][wr + m * 16 + lrow][lk]);
  };

#define RDB1(S, KK)                                                                   \
  _Pragma("unroll")                                                                   \
  for (int n = 0; n < 4; n++) {                                                       \
    const int lk = ((KK) * 32 + lkhi) ^ swz;                                          \
    bf1k[n] = *reinterpret_cast<const short8*>(&lB1[S][wc + n * 16 + lrow][lk]);      \
  }
#define RDB2(S, KK)                                                                   \
  _Pragma("unroll")                                                                   \
  for (int n = 0; n < 4; n++) {                                                       \
    const int lk = ((KK) * 32 + lkhi) ^ swz;                                          \
    bf2k[n] = *reinterpret_cast<const short8*>(&lB2[S][wc + n * 16 + lrow][lk]);      \
  }
#define MM16A(A0, A1, A2, A3)                                             \
  _Pragma("unroll")                                                       \
  for (int n = 0; n < 4; n++) {                                           \
    acc1[0][n] = MFMA16x16(A0, bf1k[n], acc1[0][n], 0, 0, 0);             \
    acc1[1][n] = MFMA16x16(A1, bf1k[n], acc1[1][n], 0, 0, 0);             \
    acc1[2][n] = MFMA16x16(A2, bf1k[n], acc1[2][n], 0, 0, 0);             \
    acc1[3][n] = MFMA16x16(A3, bf1k[n], acc1[3][n], 0, 0, 0);             \
  }
#define MM16B(A0, A1, A2, A3)                                             \
  _Pragma("unroll")                                                       \
  for (int n = 0; n < 4; n++) {                                           \
    acc2[0][n] = MFMA16x16(A0, bf2k[n], acc2[0][n], 0, 0, 0);             \
    acc2[1][n] = MFMA16x16(A1, bf2k[n], acc2[1][n], 0, 0, 0);             \
    acc2[2][n] = MFMA16x16(A2, bf2k[n], acc2[2][n], 0, 0, 0);             \
    acc2[3][n] = MFMA16x16(A3, bf2k[n], acc2[3][n], 0, 0, 0);             \
  }
// Ledger per tile t (per-wave, FIFO): A(t):4 @t-1P1, B1/B2(t):4 @t-1P2.
// End-P4 vmcnt(2) guards A,B1(t+1); end-P1 vmcnt(4) guards B2(t).
// WAR-free: P1 writes afA (prev cluster read afB); P3 writes afB (prev read afA);
// P2 writes bf2k (prev cluster read bf1k); P1/P3 write bf1k (prev read bf2k).
#define GTILE(S, SN, TS)                                                 \
  /* P1 */                                                               \
  afA0 = rdA(S, 0, 0); afA1 = rdA(S, 1, 0);                              \
  afA2 = rdA(S, 2, 0); afA3 = rdA(S, 3, 0);                              \
  RDB1(S, 0);                                                            \
  stA2(SN, TS, 0); stA2(SN, TS, 2);                                      \
  BAR(); LGKM0;                                                          \
  PRIO1; MM16A(afA0, afA1, afA2, afA3) PRIO0; SCB;                       \
  VMWAIT(4);                                                             \
  BAR();                                                                 \
  /* P2 */                                                               \
  RDB2(S, 0);                                                            \
  stB1s(SN, TS); stB2s(SN, TS);                                          \
  BAR(); LGKM0;                                                          \
  PRIO1; MM16B(afA0, afA1, afA2, afA3) PRIO0; SCB;                       \
  BAR();                                                                 \
  /* P3 */                                                               \
  afB0 = rdA(S, 0, 1); afB1 = rdA(S, 1, 1);                              \
  afB2 = rdA(S, 2, 1); afB3 = rdA(S, 3, 1);                              \
  RDB1(S, 1);                                                            \
  BAR(); LGKM0;                                                          \
  PRIO1; MM16A(afB0, afB1, afB2, afB3) PRIO0; SCB;                       \
  BAR();                                                                 \
  /* P4 */                                                               \
  RDB2(S, 1);                                                            \
  BAR(); LGKM0;                                                          \
  PRIO1; MM16B(afB0, afB1, afB2, afB3) PRIO0; SCB;                       \
  VMWAIT(2);                                                             \
  BAR();

  // prologue: stage tile 0 into slot 0 (8 issues); need first 6 -> vmcnt(2)
  stA2(0, 0, 0); stA2(0, 0, 2); stB1s(0, 0); stB2s(0, 0);
  VMWAIT(2);
  BAR();

  #pragma unroll 1
  for (int i = 0; i < 16; i++) {
    const int S = i & 1, SN = S ^ 1;
    const int TS = (i < 15) ? i + 1 : 15;   // last iter: harmless restage
    GTILE(S, SN, TS)
  }
  VMWAIT(0);
#undef GTILE
#undef MM16A
#undef MM16B
#undef RDB1
#undef RDB2

  // epilogue: bias + reasoning-mask blend; C/D: col=lane&15, row=(lane>>4)*4+r
  #pragma unroll
  for (int m = 0; m < 4; m++) {
    const int rbase = m0 + wr + m * 16 + ((lane >> 4) << 2);
    #pragma unroll
    for (int n = 0; n < 4; n++) {
      const int col = n0 + wc + n * 16 + lrow;
      const float bias1 = B1b[col];
      const float bias2 = B2b[col];
      #pragma unroll
      for (int r = 0; r < 4; r++) {
        const int row = rbase + r;
        const float mk = MASK[row];
        const float val = (acc1[m][n][r] + bias1) * (1.f - mk) +
                          (acc2[m][n][r] + bias2) * mk;
        OUT[(size_t)row * HID + col] = __float2bfloat16(val);
      }
    }
  }
}

// ---------------- plain GEMM (single B): V-proj and out-proj ----------------
// BM=256 BN=128 BK=64, 512 thr. Triple-buffered LDS, vmcnt(6) never 0,
// per-kk register sets (WAR-free phase overlap).
template<bool OUTF32>
__global__ __launch_bounds__(512, 2) void plain8_kernel(
    const short* __restrict__ A, const short* __restrict__ WT,
    const float* __restrict__ BIAS, void* __restrict__ OUTv)
{
  __shared__ short lA[3][256][64];    // 96 KB
  __shared__ short lB[3][128][64];    // 48 KB

  // linear map (== dispatch order)
  const int d = blockIdx.x;
  const int bx = d & 31, by = d >> 5;

  const int m0 = bx * 256, n0 = by * 128;
  const int tid = threadIdx.x, lane = tid & 63, w = tid >> 6;
  const int wr = (w >> 1) * 64, wc = (w & 1) * 64;
  const int lrow = lane & 15, lkhi = (lane >> 4) << 3;
  const int swz = (lrow & 7) << 3;
  const int srow = lane >> 3, scol = (lane & 7) << 3;

  f32x4 acc[4][4] = {};
  short8 paf[2][4], pbf[2][4];   // per-kk sets, all indices compile-time

  auto stTrip = [&](int slot, int kt, int t) {  // t=0 -> A{0,1,2}; t=1 -> A3,B0,B1
    const int k0 = kt * 64;
    if (t == 0) {
      #pragma unroll
      for (int i = 0; i < 3; i++) {
        const int chunk = w * 4 + i;
        gload16(&A[(size_t)(m0 + chunk * 8 + srow) * HID + k0 + scol],
                &lA[slot][chunk * 8][0]);
      }
    } else {
      const int chunk = w * 4 + 3;
      gload16(&A[(size_t)(m0 + chunk * 8 + srow) * HID + k0 + scol],
              &lA[slot][chunk * 8][0]);
      #pragma unroll
      for (int i = 0; i < 2; i++) {
        const int bchunk = w * 2 + i;
        gload16(&WT[(size_t)(n0 + bchunk * 8 + srow) * HID + k0 + scol],
                &lB[slot][bchunk * 8][0]);
      }
    }
  };

#define RDP(S, KK)                                                                    \
  _Pragma("unroll")                                                                   \
  for (int m = 0; m < 4; m++) {                                                       \
    const int lk = ((KK) * 32 + lkhi) ^ swz;                                          \
    paf[KK][m] = *reinterpret_cast<const short8*>(&lA[S][wr + m * 16 + lrow][lk]);    \
    pbf[KK][m] = *reinterpret_cast<const short8*>(&lB[S][wc + m * 16 + lrow][lk]);    \
  }
#define PMM16(KK)                                                                     \
  _Pragma("unroll")                                                                   \
  for (int m = 0; m < 4; m++)                                                         \
    _Pragma("unroll")                                                                 \
    for (int n = 0; n < 4; n++)                                                       \
      acc[m][n] = MFMA16x16(paf[KK][m], pbf[KK][n], acc[m][n], 0, 0, 0);

  // prologue: tiles 0,1 into slots 0,1 (12 issues); need tile0 -> vmcnt(6)
  stTrip(0, 0, 0); stTrip(0, 0, 1);
  stTrip(1, 1, 0); stTrip(1, 1, 1);
  VMWAIT(6);
  BAR();

  int s = 0, s2 = 2;
  #pragma unroll 1
  for (int t = 0; t < 16; t++) {
    const int TS = (t < 14) ? t + 2 : 15;   // tail: harmless restage
    // P1 (writes set0; prev cluster read set1 -> WAR-free)
    RDP(s, 0)
    stTrip(s2, TS, 0);
    BAR(); LGKM0;
    PRIO1; PMM16(0) PRIO0; SCB;
    BAR();
    // P2 (writes set1; prev cluster read set0 -> WAR-free)
    RDP(s, 1)
    stTrip(s2, TS, 1);
    BAR(); LGKM0;
    PRIO1; PMM16(1) PRIO0; SCB;
    VMWAIT(6);     // guards tile t+1 (6 issues of t+2 in flight), never 0
    BAR();
    s = (s == 2) ? 0 : s + 1;
    s2 = (s2 == 2) ? 0 : s2 + 1;
  }
  VMWAIT(0);
#undef PMM16
#undef RDP

  #pragma unroll
  for (int m = 0; m < 4; m++) {
    const int rbase = m0 + wr + m * 16 + ((lane >> 4) << 2);
    #pragma unroll
    for (int n = 0; n < 4; n++) {
      const int col = n0 + wc + n * 16 + lrow;
      const float bias = BIAS[col];
      #pragma unroll
      for (int r = 0; r < 4; r++) {
        const float val = acc[m][n][r] + bias;
        const size_t oidx = (size_t)(rbase + r) * HID + col;
        if (OUTF32) ((float*)OUTv)[oidx] = val;
        else ((__hip_bfloat16*)OUTv)[oidx] = __float2bfloat16(val);
      }
    }
  }
}

// ---------------- per-token 16x16 cross-head attention ----------------------
// out row = b*2048 + h*128 + s/16, col = (s%16)*64 + d, stored with the
// 64-block swizzle (d ^= (row&7)<<3) so the final GEMM can global_load_lds it.
__global__ __launch_bounds__(256) void attn_kernel(
    const __hip_bfloat16* __restrict__ Q, const __hip_bfloat16* __restrict__ K,
    const __hip_bfloat16* __restrict__ V, __hip_bfloat16* __restrict__ O)
{
  const int t = blockIdx.x;
  const int b = t >> 11, s = t & 2047;
  __shared__ float sQ[16][68], sK[16][68], sV[16][68];
  __shared__ float sA[16][17];
  const int tid = threadIdx.x;
  const size_t tb = (size_t)t * HID;

  {
    const int h = tid >> 4, d0 = (tid & 15) << 2;
    const int o = (h << 6) + d0;
    const short4v qv = *reinterpret_cast<const short4v*>(&((const short*)Q)[tb + o]);
    const short4v kv = *reinterpret_cast<const short4v*>(&((const short*)K)[tb + o]);
    const short4v vv = *reinterpret_cast<const short4v*>(&((const short*)V)[tb + o]);
    #pragma unroll
    for (int j = 0; j < 4; j++) {
      sQ[h][d0 + j] = bs2f(qv[j]);
      sK[h][d0 + j] = bs2f(kv[j]);
      sV[h][d0 + j] = bs2f(vv[j]);
    }
  }
  __syncthreads();

  const int h = tid >> 4, e = tid & 15;
  float sc = 0.f;
  #pragma unroll
  for (int dd = 0; dd < 64; dd++) sc += sQ[h][dd] * sK[e][dd];
  sc *= 0.125f;

  float mx = sc;
  mx = fmaxf(mx, __shfl_xor(mx, 1));
  mx = fmaxf(mx, __shfl_xor(mx, 2));
  mx = fmaxf(mx, __shfl_xor(mx, 4));
  mx = fmaxf(mx, __shfl_xor(mx, 8));
  const float p = __expf(sc - mx);
  float sm = p;
  sm += __shfl_xor(sm, 1);
  sm += __shfl_xor(sm, 2);
  sm += __shfl_xor(sm, 4);
  sm += __shfl_xor(sm, 8);
  sA[h][e] = p / sm;
  __syncthreads();

  const int row7 = (s >> 4) & 7;
  const size_t ob = ((size_t)b * 2048 + (s >> 4)) * HID + ((size_t)(s & 15) << 6);
  {
    const int hh = tid >> 4, d4 = (tid & 15) << 2;
    f32x4 o = {0.f, 0.f, 0.f, 0.f};
    #pragma unroll
    for (int e2 = 0; e2 < 16; e2++) {
      const float a = sA[hh][e2];
      #pragma unroll
      for (int j = 0; j < 4; j++) o[j] += a * sV[e2][d4 + j];
    }
    short4v ov;
    #pragma unroll
    for (int j = 0; j < 4; j++) ov[j] = f2bs(o[j]);
    *reinterpret_cast<short4v*>(
        &((short*)O)[ob + (size_t)hh * 128 * HID + (d4 ^ (row7 << 3))]) = ov;
  }
}

extern "C" void kernel_launch(void* const* d_in, const int* in_sizes, int n_in,
                              void* d_out, int out_size, void* d_ws, size_t ws_size,
                              hipStream_t stream) {
  (void)in_sizes; (void)n_in; (void)out_size; (void)ws_size;
  const float* x   = (const float*)d_in[0];
  const float* rm  = (const float*)d_in[1];
  const float* Wq  = (const float*)d_in[2];
  const float* bq  = (const float*)d_in[3];
  const float* Wk  = (const float*)d_in[4];
  const float* bk  = (const float*)d_in[5];
  const float* Wv  = (const float*)d_in[6];
  const float* bv  = (const float*)d_in[7];
  const float* Wqr = (const float*)d_in[8];
  const float* bqr = (const float*)d_in[9];
  const float* Wkr = (const float*)d_in[10];
  const float* bkr = (const float*)d_in[11];
  const float* Wo  = (const float*)d_in[12];
  const float* bo  = (const float*)d_in[13];

  // ws: [0:12M) WT (Wq,Wqr,Wk,Wkr,Wv,Wo) | [12:28M) qg | [28:44M) vv | [44:60M) ar
  char* ws = (char*)d_ws;
  short* wt = (short*)ws;
  __hip_bfloat16* qg = (__hip_bfloat16*)(ws + 12u * 1024 * 1024);
  __hip_bfloat16* vv = (__hip_bfloat16*)(ws + 28u * 1024 * 1024);
  __hip_bfloat16* ar = (__hip_bfloat16*)(ws + 44u * 1024 * 1024);
  // d_out (32 MiB fp32) doubles as scratch until the final GEMM rewrites it:
  short* xb = (short*)d_out;                                        // [0:16M)
  __hip_bfloat16* kg = (__hip_bfloat16*)((char*)d_out + 16u * 1024 * 1024);  // [16:32M)

  prep_kernel<<<dim3(5632), 256, 0, stream>>>(Wq, Wqr, Wk, Wkr, Wv, Wo, x, wt, xb);
  gated8_kernel<<<dim3(512), 512, 0, stream>>>(xb, wt, bq, bqr, bk, bkr, rm, qg, kg);
  plain8_kernel<false><<<dim3(256), 512, 0, stream>>>(xb, wt + (size_t)4 * WT_ELEMS, bv, vv);
  attn_kernel<<<dim3(NTOK), 256, 0, stream>>>(qg, kg, vv, ar);
  plain8_kernel<true><<<dim3(256), 512, 0, stream>>>((const short*)ar,
                                                     wt + (size_t)5 * WT_ELEMS, bo, d_out);
}

// Round 10
// 145.178 us; speedup vs baseline: 1.1522x; 1.0135x over previous
//
#include <hip/hip_runtime.h>
#include <hip/hip_bf16.h>

// ReasoningMultiHeadAttention: B=4 S=2048 HID=1024 NH=16 DH=64. All I/O fp32.
// prep: 6x W -> bf16 W^T pre-swizzled (wt, ws) ; x -> bf16 xb pre-swizzled (in d_out!)
// gated8: dual-B GEMM. R10: ONE barrier per K-tile + per-wave lgkmcnt LADDER
//   (never-0 partial waits) so LDS reads of one wave overlap MFMA of others.
// plain8<bf16>: xb @ WvT + bv -> vv ; triple-buffered LDS, ladder, vmcnt(6)
// attn: per-token 16x16 cross-head attn -> ar (ws, swizzled+scrambled)
// plain8<f32>: ar @ WoT + bo -> d_out (overwrites xb/kg scratch, all dead)
// ws usage: [0:12M wt][12:28M qg][28:44M vv][44:60M ar] = 60 MB
// d_out scratch: [0:16M xb][16:32M kg] until final GEMM rewrites all of d_out.

typedef __attribute__((ext_vector_type(8))) short short8;
typedef __attribute__((ext_vector_type(4))) short short4v;
typedef __attribute__((ext_vector_type(4))) float f32x4;

#define HID 1024
#define NTOK 8192
#define WT_ELEMS (1024 * 1024)

__device__ __forceinline__ short f2bs(float f) {
  __hip_bfloat16 h = __float2bfloat16(f);
  return *reinterpret_cast<short*>(&h);
}
__device__ __forceinline__ float bs2f(short s) {
  __hip_bfloat16 h;
  *reinterpret_cast<short*>(&h) = s;
  return __bfloat162float(h);
}
__device__ __forceinline__ void gload16(const void* g, void* l) {
  __builtin_amdgcn_global_load_lds(
      (const __attribute__((address_space(1))) void*)g,
      (__attribute__((address_space(3))) void*)l, 16, 0, 0);
}

#define BAR() asm volatile("s_barrier" ::: "memory")
#define VMWAIT(N) asm volatile("s_waitcnt vmcnt(" #N ")" ::: "memory")
#define LGKMW(N) do { asm volatile("s_waitcnt lgkmcnt(" #N ")" ::: "memory"); \
                      __builtin_amdgcn_sched_barrier(0); } while (0)
#define SCB __builtin_amdgcn_sched_barrier(0)
#define PRIO1 __builtin_amdgcn_s_setprio(1)
#define PRIO0 __builtin_amdgcn_s_setprio(0)
#define MFMA16x16 __builtin_amdgcn_mfma_f32_16x16x32_bf16

// ---------------- prep: W transposes (z<6) + x fp32->bf16 convert ----------
// WT[n][ (k&~63) | ((k&63) ^ ((n&7)<<3)) ] = bf16(W[k][n])
// XB[row][ (k&~63) | ((k&63) ^ ((row&7)<<3)) ] = bf16(x[row][k])
__global__ __launch_bounds__(256) void prep_kernel(
    const float* __restrict__ W0, const float* __restrict__ W1,
    const float* __restrict__ W2, const float* __restrict__ W3,
    const float* __restrict__ W4, const float* __restrict__ W5,
    const float* __restrict__ X, short* __restrict__ WT, short* __restrict__ XB)
{
  __shared__ short sT[64][68];
  const int bid = blockIdx.x, tid = threadIdx.x;
  if (bid < 1536) {
    const int z = bid >> 8, rem = bid & 255;
    const float* W = z == 0 ? W0 : z == 1 ? W1 : z == 2 ? W2 : z == 3 ? W3
                   : z == 4 ? W4 : W5;
    short* OUT = WT + (size_t)z * WT_ELEMS;
    const int k0 = (rem & 15) * 64, n0 = (rem >> 4) * 64;
    #pragma unroll
    for (int i = 0; i < 4; i++) {
      const int li = tid + i * 256;
      const int kr = li >> 4, c4 = (li & 15) << 2;
      const f32x4 wv = *reinterpret_cast<const f32x4*>(&W[(size_t)(k0 + kr) * HID + n0 + c4]);
      short4v s4;
      #pragma unroll
      for (int j = 0; j < 4; j++) s4[j] = f2bs(wv[j]);
      *reinterpret_cast<short4v*>(&sT[kr][c4]) = s4;
    }
    __syncthreads();
    #pragma unroll
    for (int i = 0; i < 4; i++) {
      const int li = tid + i * 256;
      const int nr = li >> 4, k4 = (li & 15) << 2;
      short4v o;
      #pragma unroll
      for (int j = 0; j < 4; j++) o[j] = sT[k4 + j][nr];
      const int kcol = (k0 + k4) ^ ((nr & 7) << 3);
      *reinterpret_cast<short4v*>(&OUT[(size_t)(n0 + nr) * HID + kcol]) = o;
    }
  } else {
    const int gid = (bid - 1536) * 256 + tid;      // 0..1048575
    const int row = gid >> 7, kc = (gid & 127) << 3;
    const f32x4 a = *reinterpret_cast<const f32x4*>(&X[(size_t)row * HID + kc]);
    const f32x4 b = *reinterpret_cast<const f32x4*>(&X[(size_t)row * HID + kc + 4]);
    short8 s;
    #pragma unroll
    for (int j = 0; j < 4; j++) { s[j] = f2bs(a[j]); s[4 + j] = f2bs(b[j]); }
    const int phys = (kc & ~63) | ((kc & 63) ^ ((row & 7) << 3));
    *reinterpret_cast<short8*>(&XB[(size_t)row * HID + phys]) = s;
  }
}

// ---------------- gated GEMM: z=0 -> qg, z=1 -> kg --------------------------
// BM=256 BN=128 BK=64, 512 thr (8 waves, 4M x 2N), dual-B, linear block map.
// One barrier/K-tile; lgkmcnt ladder 12/8/4/0; vmcnt(0) pre-satisfied at tile end.
__global__ __launch_bounds__(512, 2) void gated8_kernel(
    const short* __restrict__ XB, const short* __restrict__ WTbase,
    const float* __restrict__ bq, const float* __restrict__ bqr,
    const float* __restrict__ bk, const float* __restrict__ bkr,
    const float* __restrict__ MASK,
    __hip_bfloat16* __restrict__ qg, __hip_bfloat16* __restrict__ kg)
{
  __shared__ short lA[2][256][64];    // 64 KB
  __shared__ short lB1[2][128][64];   // 32 KB
  __shared__ short lB2[2][128][64];   // 32 KB

  const int d = blockIdx.x;
  const int bx = d & 31, byz = d >> 5;
  const int by = byz & 7, z = byz >> 3;

  const short* W1T = WTbase + (size_t)(2 * z) * WT_ELEMS;
  const short* W2T = W1T + WT_ELEMS;
  const float* B1b = z ? bk : bq;
  const float* B2b = z ? bkr : bqr;
  __hip_bfloat16* OUT = z ? kg : qg;

  const int m0 = bx * 256, n0 = by * 128;
  const int tid = threadIdx.x, lane = tid & 63, w = tid >> 6;
  const int wr = (w >> 1) * 64, wc = (w & 1) * 64;
  const int lrow = lane & 15, lkhi = (lane >> 4) << 3;
  const int swz = (lrow & 7) << 3;
  const int srow = lane >> 3, scol = (lane & 7) << 3;

  f32x4 acc1[4][4] = {}, acc2[4][4] = {};
  short8 bf1k[4], bf2k[4], bf1b[4];          // bf2k reused for kk1
  short8 afA0, afA1, afA2, afA3;             // A frags kk0
  short8 afB0, afB1, afB2, afB3;             // A frags kk1

  auto stA2 = [&](int slot, int kt, int i0) {   // 2 A-issues
    const int k0 = kt * 64;
    #pragma unroll
    for (int i = 0; i < 2; i++) {
      const int chunk = w * 4 + i0 + i;
      gload16(&XB[(size_t)(m0 + chunk * 8 + srow) * HID + k0 + scol],
              &lA[slot][chunk * 8][0]);
    }
  };
  auto stB1s = [&](int slot, int kt) {          // 2 B1-issues
    const int k0 = kt * 64;
    #pragma unroll
    for (int i = 0; i < 2; i++) {
      const int chunk = w * 2 + i;
      gload16(&W1T[(size_t)(n0 + chunk * 8 + srow) * HID + k0 + scol],
              &lB1[slot][chunk * 8][0]);
    }
  };
  auto stB2s = [&](int slot, int kt) {          // 2 B2-issues
    const int k0 = kt * 64;
    #pragma unroll
    for (int i = 0; i < 2; i++) {
      const int chunk = w * 2 + i;
      gload16(&W2T[(size_t)(n0 + chunk * 8 + srow) * HID + k0 + scol],
              &lB2[slot][chunk * 8][0]);
    }
  };
  auto rdA = [&](int s, int m, int kk) -> short8 {
    const int lk = (kk * 32 + lkhi) ^ swz;
    return *reinterpret_cast<const short8*>(&lA[s][wr + m * 16 + lrow][lk]);
  };

#define RDB1(DST, S, KK)                                                              \
  _Pragma("unroll")                                                                   \
  for (int n = 0; n < 4; n++) {                                                       \
    const int lk = ((KK) * 32 + lkhi) ^ swz;                                          \
    DST[n] = *reinterpret_cast<const short8*>(&lB1[S][wc + n * 16 + lrow][lk]);       \
  }
#define RDB2(DST, S, KK)                                                              \
  _Pragma("unroll")                                                                   \
  for (int n = 0; n < 4; n++) {                                                       \
    const int lk = ((KK) * 32 + lkhi) ^ swz;                                          \
    DST[n] = *reinterpret_cast<const short8*>(&lB2[S][wc + n * 16 + lrow][lk]);       \
  }
#define MMC1(A0, A1, A2, A3, BF)                                          \
  _Pragma("unroll")                                                       \
  for (int n = 0; n < 4; n++) {                                           \
    acc1[0][n] = MFMA16x16(A0, BF[n], acc1[0][n], 0, 0, 0);               \
    acc1[1][n] = MFMA16x16(A1, BF[n], acc1[1][n], 0, 0, 0);               \
    acc1[2][n] = MFMA16x16(A2, BF[n], acc1[2][n], 0, 0, 0);               \
    acc1[3][n] = MFMA16x16(A3, BF[n], acc1[3][n], 0, 0, 0);               \
  }
#define MMC2(A0, A1, A2, A3, BF)                                          \
  _Pragma("unroll")                                                       \
  for (int n = 0; n < 4; n++) {                                           \
    acc2[0][n] = MFMA16x16(A0, BF[n], acc2[0][n], 0, 0, 0);               \
    acc2[1][n] = MFMA16x16(A1, BF[n], acc2[1][n], 0, 0, 0);               \
    acc2[2][n] = MFMA16x16(A2, BF[n], acc2[2][n], 0, 0, 0);               \
    acc2[3][n] = MFMA16x16(A3, BF[n], acc2[3][n], 0, 0, 0);               \
  }
// DS issue order (groups pinned by SCB): [afA 4][bf1k 4][bf2k 4][afB 4][bf1b 4]
// ladder: C1 needs 1-8 -> lgkm(12); C2 needs 9-12 -> lgkm(8);
// then issue [bf2k' 4]; C3 needs 13-20 -> lgkm(4); C4 needs 21-24 -> lgkm(0).
// Stages (VMEM) issued early, waited at tile end (pre-satisfied by then).
#define GTILE(S, SN, TS)                                                 \
  afA0 = rdA(S, 0, 0); afA1 = rdA(S, 1, 0);                              \
  afA2 = rdA(S, 2, 0); afA3 = rdA(S, 3, 0);                              \
  SCB;                                                                   \
  RDB1(bf1k, S, 0);                                                      \
  SCB;                                                                   \
  RDB2(bf2k, S, 0);                                                      \
  SCB;                                                                   \
  afB0 = rdA(S, 0, 1); afB1 = rdA(S, 1, 1);                              \
  afB2 = rdA(S, 2, 1); afB3 = rdA(S, 3, 1);                              \
  SCB;                                                                   \
  RDB1(bf1b, S, 1);                                                      \
  SCB;                                                                   \
  stA2(SN, TS, 0); stA2(SN, TS, 2); stB1s(SN, TS); stB2s(SN, TS);        \
  SCB;                                                                   \
  LGKMW(12);                                                             \
  PRIO1; MMC1(afA0, afA1, afA2, afA3, bf1k) PRIO0; SCB;                  \
  LGKMW(8);                                                              \
  PRIO1; MMC2(afA0, afA1, afA2, afA3, bf2k) PRIO0; SCB;                  \
  RDB2(bf2k, S, 1);                                                      \
  SCB;                                                                   \
  LGKMW(4);                                                              \
  PRIO1; MMC1(afB0, afB1, afB2, afB3, bf1b) PRIO0; SCB;                  \
  LGKMW(0);                                                              \
  PRIO1; MMC2(afB0, afB1, afB2, afB3, bf2k) PRIO0; SCB;                  \
  VMWAIT(0);                                                             \
  BAR();

  // prologue: stage tile 0 into slot 0 (8 issues)
  stA2(0, 0, 0); stA2(0, 0, 2); stB1s(0, 0); stB2s(0, 0);
  VMWAIT(0);
  BAR();

  #pragma unroll 1
  for (int i = 0; i < 16; i++) {
    const int S = i & 1, SN = S ^ 1;
    const int TS = (i < 15) ? i + 1 : 15;   // last iter: harmless restage
    GTILE(S, SN, TS)
  }
#undef GTILE
#undef MMC1
#undef MMC2
#undef RDB1
#undef RDB2

  // epilogue: bias + reasoning-mask blend; C/D: col=lane&15, row=(lane>>4)*4+r
  #pragma unroll
  for (int m = 0; m < 4; m++) {
    const int rbase = m0 + wr + m * 16 + ((lane >> 4) << 2);
    #pragma unroll
    for (int n = 0; n < 4; n++) {
      const int col = n0 + wc + n * 16 + lrow;
      const float bias1 = B1b[col];
      const float bias2 = B2b[col];
      #pragma unroll
      for (int r = 0; r < 4; r++) {
        const int row = rbase + r;
        const float mk = MASK[row];
        const float val = (acc1[m][n][r] + bias1) * (1.f - mk) +
                          (acc2[m][n][r] + bias2) * mk;
        OUT[(size_t)row * HID + col] = __float2bfloat16(val);
      }
    }
  }
}

// ---------------- plain GEMM (single B): V-proj and out-proj ----------------
// BM=256 BN=128 BK=64, 512 thr. Triple-buffered LDS; one barrier/K-tile;
// ladder lgkm(8)/(0); vmcnt(6) never 0.
template<bool OUTF32>
__global__ __launch_bounds__(512, 2) void plain8_kernel(
    const short* __restrict__ A, const short* __restrict__ WT,
    const float* __restrict__ BIAS, void* __restrict__ OUTv)
{
  __shared__ short lA[3][256][64];    // 96 KB
  __shared__ short lB[3][128][64];    // 48 KB

  const int d = blockIdx.x;
  const int bx = d & 31, by = d >> 5;

  const int m0 = bx * 256, n0 = by * 128;
  const int tid = threadIdx.x, lane = tid & 63, w = tid >> 6;
  const int wr = (w >> 1) * 64, wc = (w & 1) * 64;
  const int lrow = lane & 15, lkhi = (lane >> 4) << 3;
  const int swz = (lrow & 7) << 3;
  const int srow = lane >> 3, scol = (lane & 7) << 3;

  f32x4 acc[4][4] = {};
  short8 paf[2][4], pbf[2][4];   // per-kk sets, compile-time indexed

  auto stTrip = [&](int slot, int kt, int t) {  // t=0 -> A{0,1,2}; t=1 -> A3,B0,B1
    const int k0 = kt * 64;
    if (t == 0) {
      #pragma unroll
      for (int i = 0; i < 3; i++) {
        const int chunk = w * 4 + i;
        gload16(&A[(size_t)(m0 + chunk * 8 + srow) * HID + k0 + scol],
                &lA[slot][chunk * 8][0]);
      }
    } else {
      const int chunk = w * 4 + 3;
      gload16(&A[(size_t)(m0 + chunk * 8 + srow) * HID + k0 + scol],
              &lA[slot][chunk * 8][0]);
      #pragma unroll
      for (int i = 0; i < 2; i++) {
        const int bchunk = w * 2 + i;
        gload16(&WT[(size_t)(n0 + bchunk * 8 + srow) * HID + k0 + scol],
                &lB[slot][bchunk * 8][0]);
      }
    }
  };

#define RDP(S, KK)                                                                    \
  _Pragma("unroll")                                                                   \
  for (int m = 0; m < 4; m++) {                                                       \
    const int lk = ((KK) * 32 + lkhi) ^ swz;                                          \
    paf[KK][m] = *reinterpret_cast<const short8*>(&lA[S][wr + m * 16 + lrow][lk]);    \
    pbf[KK][m] = *reinterpret_cast<const short8*>(&lB[S][wc + m * 16 + lrow][lk]);    \
  }
#define PMM16(KK)                                                                     \
  _Pragma("unroll")                                                                   \
  for (int m = 0; m < 4; m++)                                                         \
    _Pragma("unroll")                                                                 \
    for (int n = 0; n < 4; n++)                                                       \
      acc[m][n] = MFMA16x16(paf[KK][m], pbf[KK][n], acc[KK == 0 ? m : m][n], 0, 0, 0);

  // prologue: tiles 0,1 into slots 0,1 (12 issues); need tile0 -> vmcnt(6)
  stTrip(0, 0, 0); stTrip(0, 0, 1);
  stTrip(1, 1, 0); stTrip(1, 1, 1);
  VMWAIT(6);
  BAR();

  int s = 0, s2 = 2;
  #pragma unroll 1
  for (int t = 0; t < 16; t++) {
    const int TS = (t < 14) ? t + 2 : 15;   // tail: harmless restage
    // DS issue: [paf0,pbf0 8][paf1,pbf1 8]; ladder lgkm(8) -> C0, lgkm(0) -> C1
    RDP(s, 0)
    SCB;
    RDP(s, 1)
    SCB;
    stTrip(s2, TS, 0); stTrip(s2, TS, 1);
    SCB;
    LGKMW(8);
    PRIO1; PMM16(0) PRIO0; SCB;
    LGKMW(0);
    PRIO1; PMM16(1) PRIO0; SCB;
    VMWAIT(6);     // guards tile t+1 (6 issues of t+2 in flight), never 0
    BAR();
    s = (s == 2) ? 0 : s + 1;
    s2 = (s2 == 2) ? 0 : s2 + 1;
  }
#undef PMM16
#undef RDP

  #pragma unroll
  for (int m = 0; m < 4; m++) {
    const int rbase = m0 + wr + m * 16 + ((lane >> 4) << 2);
    #pragma unroll
    for (int n = 0; n < 4; n++) {
      const int col = n0 + wc + n * 16 + lrow;
      const float bias = BIAS[col];
      #pragma unroll
      for (int r = 0; r < 4; r++) {
        const float val = acc[m][n][r] + bias;
        const size_t oidx = (size_t)(rbase + r) * HID + col;
        if (OUTF32) ((float*)OUTv)[oidx] = val;
        else ((__hip_bfloat16*)OUTv)[oidx] = __float2bfloat16(val);
      }
    }
  }
}

// ---------------- per-token 16x16 cross-head attention ----------------------
// out row = b*2048 + h*128 + s/16, col = (s%16)*64 + d, stored with the
// 64-block swizzle (d ^= (row&7)<<3) so the final GEMM can global_load_lds it.
__global__ __launch_bounds__(256) void attn_kernel(
    const __hip_bfloat16* __restrict__ Q, const __hip_bfloat16* __restrict__ K,
    const __hip_bfloat16* __restrict__ V, __hip_bfloat16* __restrict__ O)
{
  const int t = blockIdx.x;
  const int b = t >> 11, s = t & 2047;
  __shared__ float sQ[16][68], sK[16][68], sV[16][68];
  __shared__ float sA[16][17];
  const int tid = threadIdx.x;
  const size_t tb = (size_t)t * HID;

  {
    const int h = tid >> 4, d0 = (tid & 15) << 2;
    const int o = (h << 6) + d0;
    const short4v qv = *reinterpret_cast<const short4v*>(&((const short*)Q)[tb + o]);
    const short4v kv = *reinterpret_cast<const short4v*>(&((const short*)K)[tb + o]);
    const short4v vv = *reinterpret_cast<const short4v*>(&((const short*)V)[tb + o]);
    #pragma unroll
    for (int j = 0; j < 4; j++) {
      sQ[h][d0 + j] = bs2f(qv[j]);
      sK[h][d0 + j] = bs2f(kv[j]);
      sV[h][d0 + j] = bs2f(vv[j]);
    }
  }
  __syncthreads();

  const int h = tid >> 4, e = tid & 15;
  float sc = 0.f;
  #pragma unroll
  for (int dd = 0; dd < 64; dd++) sc += sQ[h][dd] * sK[e][dd];
  sc *= 0.125f;

  float mx = sc;
  mx = fmaxf(mx, __shfl_xor(mx, 1));
  mx = fmaxf(mx, __shfl_xor(mx, 2));
  mx = fmaxf(mx, __shfl_xor(mx, 4));
  mx = fmaxf(mx, __shfl_xor(mx, 8));
  const float p = __expf(sc - mx);
  float sm = p;
  sm += __shfl_xor(sm, 1);
  sm += __shfl_xor(sm, 2);
  sm += __shfl_xor(sm, 4);
  sm += __shfl_xor(sm, 8);
  sA[h][e] = p / sm;
  __syncthreads();

  const int row7 = (s >> 4) & 7;
  const size_t ob = ((size_t)b * 2048 + (s >> 4)) * HID + ((size_t)(s & 15) << 6);
  {
    const int hh = tid >> 4, d4 = (tid & 15) << 2;
    f32x4 o = {0.f, 0.f, 0.f, 0.f};
    #pragma unroll
    for (int e2 = 0; e2 < 16; e2++) {
      const float a = sA[hh][e2];
      #pragma unroll
      for (int j = 0; j < 4; j++) o[j] += a * sV[e2][d4 + j];
    }
    short4v ov;
    #pragma unroll
    for (int j = 0; j < 4; j++) ov[j] = f2bs(o[j]);
    *reinterpret_cast<short4v*>(
        &((short*)O)[ob + (size_t)hh * 128 * HID + (d4 ^ (row7 << 3))]) = ov;
  }
}

extern "C" void kernel_launch(void* const* d_in, const int* in_sizes, int n_in,
                              void* d_out, int out_size, void* d_ws, size_t ws_size,
                              hipStream_t stream) {
  (void)in_sizes; (void)n_in; (void)out_size; (void)ws_size;
  const float* x   = (const float*)d_in[0];
  const float* rm  = (const float*)d_in[1];
  const float* Wq  = (const float*)d_in[2];
  const float* bq  = (const float*)d_in[3];
  const float* Wk  = (const float*)d_in[4];
  const float* bk  = (const float*)d_in[5];
  const float* Wv  = (const float*)d_in[6];
  const float* bv  = (const float*)d_in[7];
  const float* Wqr = (const float*)d_in[8];
  const float* bqr = (const float*)d_in[9];
  const float* Wkr = (const float*)d_in[10];
  const float* bkr = (const float*)d_in[11];
  const float* Wo  = (const float*)d_in[12];
  const float* bo  = (const float*)d_in[13];

  // ws: [0:12M) WT (Wq,Wqr,Wk,Wkr,Wv,Wo) | [12:28M) qg | [28:44M) vv | [44:60M) ar
  char* ws = (char*)d_ws;
  short* wt = (short*)ws;
  __hip_bfloat16* qg = (__hip_bfloat16*)(ws + 12u * 1024 * 1024);
  __hip_bfloat16* vv = (__hip_bfloat16*)(ws + 28u * 1024 * 1024);
  __hip_bfloat16* ar = (__hip_bfloat16*)(ws + 44u * 1024 * 1024);
  // d_out (32 MiB fp32) doubles as scratch until the final GEMM rewrites it:
  short* xb = (short*)d_out;                                        // [0:16M)
  __hip_bfloat16* kg = (__hip_bfloat16*)((char*)d_out + 16u * 1024 * 1024);  // [16:32M)

  prep_kernel<<<dim3(5632), 256, 0, stream>>>(Wq, Wqr, Wk, Wkr, Wv, Wo, x, wt, xb);
  gated8_kernel<<<dim3(512), 512, 0, stream>>>(xb, wt, bq, bqr, bk, bkr, rm, qg, kg);
  plain8_kernel<false><<<dim3(256), 512, 0, stream>>>(xb, wt + (size_t)4 * WT_ELEMS, bv, vv);
  attn_kernel<<<dim3(NTOK), 256, 0, stream>>>(qg, kg, vv, ar);
  plain8_kernel<true><<<dim3(256), 512, 0, stream>>>((const short*)ar,
                                                     wt + (size_t)5 * WT_ELEMS, bo, d_out);
}